// Round 1
// baseline (1444.119 us; speedup 1.0000x reference)
//
#include <hip/hip_runtime.h>

#define NSRC 50000
#define NDST 10000
#define NEDGE 250000
#define NREL 4
#define NF 256
#define NEG_SLOPE 0.2f

static __device__ __forceinline__ unsigned enc_f(float f) {
  unsigned u = __float_as_uint(f);
  return (u & 0x80000000u) ? ~u : (u | 0x80000000u);
}
static __device__ __forceinline__ float dec_f(unsigned u) {
  return (u & 0x80000000u) ? __uint_as_float(u & 0x7FFFFFFFu) : __uint_as_float(~u);
}
static __device__ __forceinline__ float leaky(float x) {
  return x > 0.f ? x : NEG_SLOPE * x;
}

// C[M,256] = A[M,256] @ B[256,256] (+ optional bias). 64x64 tile, K-step 16.
__global__ __launch_bounds__(256) void gemm_k(const float* __restrict__ A,
                                              const float* __restrict__ B,
                                              const float* __restrict__ bias,
                                              float* __restrict__ C, int M) {
  __shared__ float As[16][64];
  __shared__ float Bs[16][64];
  const int tid = threadIdx.x;
  const int bm = blockIdx.y * 64;
  const int bn = blockIdx.x * 64;
  const int tx = tid & 15, ty = tid >> 4;
  float acc[4][4] = {};
  for (int k0 = 0; k0 < NF; k0 += 16) {
    // stage A tile (64 rows x 16 k), transposed into As[k][m]
    {
      int m = tid >> 2;
      int kq = (tid & 3) << 2;
      int row = bm + m;
      float4 va = make_float4(0.f, 0.f, 0.f, 0.f);
      if (row < M) va = *(const float4*)(A + (size_t)row * NF + k0 + kq);
      As[kq + 0][m] = va.x; As[kq + 1][m] = va.y;
      As[kq + 2][m] = va.z; As[kq + 3][m] = va.w;
    }
    // stage B tile (16 k x 64 n)
    {
      int kk = tid >> 4;
      int n4 = (tid & 15) << 2;
      float4 vb = *(const float4*)(B + (size_t)(k0 + kk) * NF + bn + n4);
      *(float4*)&Bs[kk][n4] = vb;
    }
    __syncthreads();
    #pragma unroll
    for (int kk = 0; kk < 16; ++kk) {
      float4 a4 = *(const float4*)&As[kk][ty * 4];
      float4 b4 = *(const float4*)&Bs[kk][tx * 4];
      float av[4] = {a4.x, a4.y, a4.z, a4.w};
      float bv[4] = {b4.x, b4.y, b4.z, b4.w};
      #pragma unroll
      for (int i = 0; i < 4; ++i)
        #pragma unroll
        for (int j = 0; j < 4; ++j)
          acc[i][j] = fmaf(av[i], bv[j], acc[i][j]);
    }
    __syncthreads();
  }
  #pragma unroll
  for (int i = 0; i < 4; ++i) {
    int row = bm + ty * 4 + i;
    if (row >= M) continue;
    float4 o = make_float4(acc[i][0], acc[i][1], acc[i][2], acc[i][3]);
    if (bias) {
      o.x += bias[bn + tx * 4 + 0];
      o.y += bias[bn + tx * 4 + 1];
      o.z += bias[bn + tx * 4 + 2];
      o.w += bias[bn + tx * 4 + 3];
    }
    *(float4*)(C + (size_t)row * NF + bn + tx * 4) = o;
  }
}

// el[i][h] = dot(h[i, h*64:...], attn_l[h]); er likewise for rows < NDST.
__global__ __launch_bounds__(256) void eler_k(const float* __restrict__ h,
                                              const float* __restrict__ al,
                                              const float* __restrict__ ar,
                                              float* __restrict__ el,
                                              float* __restrict__ er) {
  int row = blockIdx.x * 4 + (threadIdx.x >> 6);
  int lane = threadIdx.x & 63;
  if (row >= NSRC) return;
  const float4 hv = *(const float4*)(h + (size_t)row * NF + lane * 4);
  const float4 a = *(const float4*)(al + lane * 4);
  float dl = hv.x * a.x + hv.y * a.y + hv.z * a.z + hv.w * a.w;
  float dr = 0.f;
  if (row < NDST) {
    const float4 b = *(const float4*)(ar + lane * 4);
    dr = hv.x * b.x + hv.y * b.y + hv.z * b.z + hv.w * b.w;
  }
  #pragma unroll
  for (int off = 1; off < 16; off <<= 1) {
    dl += __shfl_xor(dl, off);
    dr += __shfl_xor(dr, off);
  }
  if ((lane & 15) == 0) {
    int head = lane >> 4;
    el[row * 4 + head] = dl;
    if (row < NDST) er[row * 4 + head] = dr;
  }
}

__global__ void hist_k(const int* __restrict__ edst, int* __restrict__ counts) {
  int i = blockIdx.x * blockDim.x + threadIdx.x;
  if (i < NEDGE) atomicAdd(&counts[edst[i]], 1);
}

__global__ __launch_bounds__(256) void scan_k(const int* __restrict__ counts,
                                              int* __restrict__ offsets,
                                              int* __restrict__ cursor) {
  __shared__ int buf[256];
  __shared__ int carry_s;
  int tid = threadIdx.x;
  if (tid == 0) carry_s = 0;
  __syncthreads();
  for (int base = 0; base < NDST; base += 256) {
    int v = (base + tid < NDST) ? counts[base + tid] : 0;
    buf[tid] = v;
    __syncthreads();
    #pragma unroll
    for (int off = 1; off < 256; off <<= 1) {
      int t = (tid >= off) ? buf[tid - off] : 0;
      __syncthreads();
      buf[tid] += t;
      __syncthreads();
    }
    int incl = buf[tid];
    int carry = carry_s;
    if (base + tid < NDST) {
      int excl = carry + incl - v;
      offsets[base + tid] = excl;
      cursor[base + tid] = excl;
    }
    __syncthreads();
    if (tid == 0) carry_s = carry + buf[255];
    __syncthreads();
  }
  if (tid == 0) offsets[NDST] = carry_s;
}

__global__ void scatter_k(const int* __restrict__ esrc, const int* __restrict__ edst,
                          int* __restrict__ cursor, int* __restrict__ perm_src,
                          int* __restrict__ perm_e) {
  int i = blockIdx.x * blockDim.x + threadIdx.x;
  if (i >= NEDGE) return;
  int pos = atomicAdd(&cursor[edst[i]], 1);
  perm_src[pos] = esrc[i];
  perm_e[pos] = i;
}

__global__ void alpha1_k(const int* __restrict__ esrc, const int* __restrict__ edst,
                         const float* __restrict__ el, const float* __restrict__ er,
                         float* __restrict__ ev, unsigned* __restrict__ emax) {
  int i = blockIdx.x * blockDim.x + threadIdx.x;
  if (i >= NEDGE) return;
  int s = esrc[i], d = edst[i];
  float4 l = *(const float4*)(el + (size_t)s * 4);
  float4 r = *(const float4*)(er + (size_t)d * 4);
  float e0 = leaky(l.x + r.x);
  float e1 = leaky(l.y + r.y);
  float e2 = leaky(l.z + r.z);
  float e3 = leaky(l.w + r.w);
  *(float4*)(ev + (size_t)i * 4) = make_float4(e0, e1, e2, e3);
  atomicMax(&emax[d * 4 + 0], enc_f(e0));
  atomicMax(&emax[d * 4 + 1], enc_f(e1));
  atomicMax(&emax[d * 4 + 2], enc_f(e2));
  atomicMax(&emax[d * 4 + 3], enc_f(e3));
}

__global__ void alpha2_k(const int* __restrict__ edst, float* __restrict__ ev,
                         const unsigned* __restrict__ emax, float* __restrict__ denom) {
  int i = blockIdx.x * blockDim.x + threadIdx.x;
  if (i >= NEDGE) return;
  int d = edst[i];
  float4 e = *(const float4*)(ev + (size_t)i * 4);
  uint4 mu = *(const uint4*)(emax + (size_t)d * 4);
  float x0 = __expf(e.x - dec_f(mu.x));
  float x1 = __expf(e.y - dec_f(mu.y));
  float x2 = __expf(e.z - dec_f(mu.z));
  float x3 = __expf(e.w - dec_f(mu.w));
  *(float4*)(ev + (size_t)i * 4) = make_float4(x0, x1, x2, x3);
  atomicAdd(&denom[d * 4 + 0], x0);
  atomicAdd(&denom[d * 4 + 1], x1);
  atomicAdd(&denom[d * 4 + 2], x2);
  atomicAdd(&denom[d * 4 + 3], x3);
}

__global__ void alpha3_k(const int* __restrict__ perm_e, const int* __restrict__ edst,
                         const float* __restrict__ ex, const float* __restrict__ denom,
                         float* __restrict__ alpha_s) {
  int p = blockIdx.x * blockDim.x + threadIdx.x;
  if (p >= NEDGE) return;
  int e = perm_e[p];
  int d = edst[e];
  float4 x = *(const float4*)(ex + (size_t)e * 4);
  float4 dn = *(const float4*)(denom + (size_t)d * 4);
  float4 o;
  o.x = x.x / fmaxf(dn.x, 1e-9f);
  o.y = x.y / fmaxf(dn.y, 1e-9f);
  o.z = x.z / fmaxf(dn.z, 1e-9f);
  o.w = x.w / fmaxf(dn.w, 1e-9f);
  *(float4*)(alpha_s + (size_t)p * 4) = o;
}

// One wave per dst node; lane owns channels [lane*4, lane*4+3] (head = lane>>4).
__global__ __launch_bounds__(256) void agg_k(const float* __restrict__ h,
                                             const int* __restrict__ offsets,
                                             const int* __restrict__ perm_src,
                                             const float* __restrict__ alpha_s,
                                             float* __restrict__ agg) {
  int d = blockIdx.x * 4 + (threadIdx.x >> 6);
  int lane = threadIdx.x & 63;
  if (d >= NDST) return;
  int beg = offsets[d], end = offsets[d + 1];
  int head = lane >> 4;
  float ax = 0.f, ay = 0.f, az = 0.f, aw = 0.f;
  for (int i = beg; i < end; ++i) {
    int src = perm_src[i];
    float a = alpha_s[(size_t)i * 4 + head];
    float4 hv = *(const float4*)(h + (size_t)src * NF + lane * 4);
    ax = fmaf(a, hv.x, ax);
    ay = fmaf(a, hv.y, ay);
    az = fmaf(a, hv.z, az);
    aw = fmaf(a, hv.w, aw);
  }
  float* p = agg + (size_t)d * NF + lane * 4;
  float4 c = *(float4*)p;
  c.x += ax; c.y += ay; c.z += az; c.w += aw;
  *(float4*)p = c;
}

__global__ void final_k(const float* __restrict__ agg, const float* __restrict__ lo,
                        float* __restrict__ out) {
  int i = blockIdx.x * blockDim.x + threadIdx.x;
  float4 a = ((const float4*)agg)[i];
  float4 l = ((const float4*)lo)[i];
  float4 o;
  o.x = fmaxf(a.x * 0.25f + l.x, 0.f);
  o.y = fmaxf(a.y * 0.25f + l.y, 0.f);
  o.z = fmaxf(a.z * 0.25f + l.z, 0.f);
  o.w = fmaxf(a.w * 0.25f + l.w, 0.f);
  ((float4*)out)[i] = o;
}

extern "C" void kernel_launch(void* const* d_in, const int* in_sizes, int n_in,
                              void* d_out, int out_size, void* d_ws, size_t ws_size,
                              hipStream_t stream) {
  const float* x      = (const float*)d_in[0];
  const float* W      = (const float*)d_in[1];
  const float* attn_l = (const float*)d_in[2];
  const float* attn_r = (const float*)d_in[3];
  const float* loop_w = (const float*)d_in[4];
  const float* loop_b = (const float*)d_in[5];
  const int* edge_src = (const int*)d_in[6];
  const int* edge_dst = (const int*)d_in[7];
  float* out = (float*)d_out;

  char* wsp = (char*)d_ws;
  size_t off = 0;
  auto alloc = [&](size_t bytes) -> char* {
    char* p = wsp + off;
    off = (off + bytes + 255) & ~(size_t)255;
    return p;
  };
  float* h       = (float*)alloc((size_t)NSRC * NF * 4);
  float* el      = (float*)alloc((size_t)NSRC * 4 * 4);
  float* er      = (float*)alloc((size_t)NDST * 4 * 4);
  int* counts    = (int*)alloc((size_t)NDST * 4);
  int* offsets   = (int*)alloc((size_t)(NDST + 1) * 4);
  int* cursor    = (int*)alloc((size_t)NDST * 4);
  int* perm_src  = (int*)alloc((size_t)NEDGE * 4);
  int* perm_e    = (int*)alloc((size_t)NEDGE * 4);
  float* ev      = (float*)alloc((size_t)NEDGE * 4 * 4);
  float* alpha_s = (float*)alloc((size_t)NEDGE * 4 * 4);
  unsigned* emax = (unsigned*)alloc((size_t)NDST * 4 * 4);
  float* denom   = (float*)alloc((size_t)NDST * 4 * 4);
  float* agg     = (float*)alloc((size_t)NDST * NF * 4);
  float* loop_o  = (float*)alloc((size_t)NDST * NF * 4);

  hipMemsetAsync(agg, 0, (size_t)NDST * NF * 4, stream);

  {
    dim3 grid(NF / 64, (NDST + 63) / 64);
    gemm_k<<<grid, 256, 0, stream>>>(x, loop_w, loop_b, loop_o, NDST);
  }

  const int EB = (NEDGE + 255) / 256;
  for (int r = 0; r < NREL; ++r) {
    const float* Wr  = W + (size_t)r * NF * NF;
    const float* alr = attn_l + (size_t)r * NF;
    const float* arr = attn_r + (size_t)r * NF;
    const int* esrc  = edge_src + (size_t)r * NEDGE;
    const int* edst  = edge_dst + (size_t)r * NEDGE;

    dim3 ggrid(NF / 64, (NSRC + 63) / 64);
    gemm_k<<<ggrid, 256, 0, stream>>>(x, Wr, nullptr, h, NSRC);
    eler_k<<<NSRC / 4, 256, 0, stream>>>(h, alr, arr, el, er);

    hipMemsetAsync(counts, 0, (size_t)NDST * 4, stream);
    hipMemsetAsync(emax, 0, (size_t)NDST * 4 * 4, stream);
    hipMemsetAsync(denom, 0, (size_t)NDST * 4 * 4, stream);

    hist_k<<<EB, 256, 0, stream>>>(edst, counts);
    scan_k<<<1, 256, 0, stream>>>(counts, offsets, cursor);
    scatter_k<<<EB, 256, 0, stream>>>(esrc, edst, cursor, perm_src, perm_e);
    alpha1_k<<<EB, 256, 0, stream>>>(esrc, edst, el, er, ev, emax);
    alpha2_k<<<EB, 256, 0, stream>>>(edst, ev, emax, denom);
    alpha3_k<<<EB, 256, 0, stream>>>(perm_e, edst, ev, denom, alpha_s);
    agg_k<<<NDST / 4, 256, 0, stream>>>(h, offsets, perm_src, alpha_s, agg);
  }
  final_k<<<(NDST * NF / 4) / 256, 256, 0, stream>>>(agg, loop_o, out);
}

// Round 2
// 348.066 us; speedup vs baseline: 4.1490x; 4.1490x over previous
//
#include <hip/hip_runtime.h>

#define NSRC 50000
#define NDST 10000
#define NEDGE 250000
#define NREL 4
#define NEG_SLOPE 0.2f

typedef unsigned short u16;
typedef __attribute__((ext_vector_type(8))) short bf16x8;
typedef __attribute__((ext_vector_type(4))) float f32x4;

#define GLD16(g, l) __builtin_amdgcn_global_load_lds( \
    (__attribute__((address_space(1))) void*)(void*)(g), \
    (__attribute__((address_space(3))) void*)(l), 16, 0, 0)

static __device__ __forceinline__ u16 f2b(float f) {
  unsigned u = __float_as_uint(f);
  unsigned r = (u + 0x7FFFu + ((u >> 16) & 1u)) >> 16;
  return (u16)r;
}
static __device__ __forceinline__ float b2f(u16 b) {
  return __uint_as_float((unsigned)b << 16);
}
static __device__ __forceinline__ float leaky(float x) {
  return x > 0.f ? x : NEG_SLOPE * x;
}

// ---------------- conversions ----------------
__global__ __launch_bounds__(256) void cvtx_k(const float* __restrict__ x,
                                              u16* __restrict__ xb) {
  int i = blockIdx.x * 256 + threadIdx.x;  // group of 4 elements
  float4 v = ((const float4*)x)[i];
  uint2 o;
  o.x = (unsigned)f2b(v.x) | ((unsigned)f2b(v.y) << 16);
  o.y = (unsigned)f2b(v.z) | ((unsigned)f2b(v.w) << 16);
  ((uint2*)xb)[i] = o;
}

// Wt[row=mat*256+n][k] = bf16( mat<4 ? W[mat][k][n] : loop_w[k][n] )
__global__ __launch_bounds__(256) void cvtw_k(const float* __restrict__ W,
                                              const float* __restrict__ loop_w,
                                              u16* __restrict__ Wt) {
  int row = blockIdx.x;        // 0..1279
  int k = threadIdx.x;         // 0..255
  int mat = row >> 8, c = row & 255;
  float v = (mat < 4) ? W[(size_t)mat * 65536 + (size_t)k * 256 + c]
                      : loop_w[(size_t)k * 256 + c];
  Wt[(size_t)row * 256 + k] = f2b(v);
}

// ---------------- GEMM: C[M, ldc-window] = A[M,256](bf16) @ B^T rows ----------------
// B given n-major: B[n][k]. Tile 128x128, BK=64, 4 waves (2x2 of 64x64).
template <int OUTMODE>  // 0: bf16 out, 1: f32 out
__global__ __launch_bounds__(256) void gemm_k(const u16* __restrict__ A,
                                              const u16* __restrict__ B,
                                              void* __restrict__ C,
                                              int M, int ldc) {
  __shared__ u16 As[128 * 64];
  __shared__ u16 Bs[128 * 64];
  const int tid = threadIdx.x;
  const int w = tid >> 6, l = tid & 63;
  const int bm = blockIdx.y * 128, bn = blockIdx.x * 128;
  const int wm = (w >> 1) * 64, wn = (w & 1) * 64;
  f32x4 acc[4][4] = {};
  const int lrow = l >> 3, lchunk = l & 7;

  for (int t = 0; t < 4; ++t) {
    const int k0 = t * 64;
    #pragma unroll
    for (int c = 0; c < 4; ++c) {
      int rb = (w * 4 + c) * 8;
      int row_in = rb + lrow;
      int colb = (lchunk * 16) ^ ((row_in & 7) << 4);
      long arow = bm + row_in;
      if (arow >= M) arow = M - 1;
      const char* ga = (const char*)A + ((size_t)arow * 256 + k0) * 2 + colb;
      GLD16(ga, (char*)As + rb * 128);
      const char* gb = (const char*)B + ((size_t)(bn + row_in) * 256 + k0) * 2 + colb;
      GLD16(gb, (char*)Bs + rb * 128);
    }
    __syncthreads();
    #pragma unroll
    for (int kk = 0; kk < 2; ++kk) {
      bf16x8 af[4], bg[4];
      #pragma unroll
      for (int m = 0; m < 4; ++m) {
        int row = wm + m * 16 + (l & 15);
        int colb = (kk * 64 + ((l >> 4) * 16)) ^ ((row & 7) << 4);
        af[m] = *(const bf16x8*)((const char*)As + row * 128 + colb);
      }
      #pragma unroll
      for (int n = 0; n < 4; ++n) {
        int row = wn + n * 16 + (l & 15);
        int colb = (kk * 64 + ((l >> 4) * 16)) ^ ((row & 7) << 4);
        bg[n] = *(const bf16x8*)((const char*)Bs + row * 128 + colb);
      }
      #pragma unroll
      for (int m = 0; m < 4; ++m)
        #pragma unroll
        for (int n = 0; n < 4; ++n)
          acc[m][n] = __builtin_amdgcn_mfma_f32_16x16x32_bf16(af[m], bg[n], acc[m][n], 0, 0, 0);
    }
    __syncthreads();
  }
  #pragma unroll
  for (int m = 0; m < 4; ++m) {
    #pragma unroll
    for (int j = 0; j < 4; ++j) {
      int row = bm + wm + m * 16 + (l >> 4) * 4 + j;
      if (row < M) {
        #pragma unroll
        for (int n = 0; n < 4; ++n) {
          int col = bn + wn + n * 16 + (l & 15);
          if (OUTMODE == 0)
            ((u16*)C)[(size_t)row * ldc + col] = f2b(acc[m][n][j]);
          else
            ((float*)C)[(size_t)row * ldc + col] = acc[m][n][j];
        }
      }
    }
  }
}

// ---------------- el/er from bf16 h ----------------
__global__ __launch_bounds__(256) void eler_k(const u16* __restrict__ hb, int ldc,
                                              int r0, int nrel,
                                              const float* __restrict__ attn_l,
                                              const float* __restrict__ attn_r,
                                              float* __restrict__ el,
                                              float* __restrict__ er) {
  int id = blockIdx.x * 4 + (threadIdx.x >> 6);
  int lane = threadIdx.x & 63;
  int row = id / nrel, rr = id - row * nrel;
  if (row >= NSRC) return;
  int r = r0 + rr;
  uint2 hv = *(const uint2*)(hb + (size_t)row * ldc + rr * 256 + lane * 4);
  float h0 = b2f((u16)(hv.x & 0xffff)), h1 = b2f((u16)(hv.x >> 16));
  float h2 = b2f((u16)(hv.y & 0xffff)), h3 = b2f((u16)(hv.y >> 16));
  float4 al = *(const float4*)(attn_l + (size_t)r * 256 + lane * 4);
  float4 ar = *(const float4*)(attn_r + (size_t)r * 256 + lane * 4);
  float dl = h0 * al.x + h1 * al.y + h2 * al.z + h3 * al.w;
  float dr = h0 * ar.x + h1 * ar.y + h2 * ar.z + h3 * ar.w;
  #pragma unroll
  for (int off = 1; off < 16; off <<= 1) {
    dl += __shfl_xor(dl, off);
    dr += __shfl_xor(dr, off);
  }
  if ((lane & 15) == 0) {
    int head = lane >> 4;
    el[(size_t)row * 16 + r * 4 + head] = dl;
    if (row < NDST) er[(size_t)row * 16 + r * 4 + head] = dr;
  }
}

// ---------------- CSR build (all 4 relations at once) ----------------
__global__ void hist_k(const int* __restrict__ edst, int* __restrict__ counts) {
  int g = blockIdx.x * 256 + threadIdx.x;
  if (g >= NREL * NEDGE) return;
  int r = g / NEDGE;
  atomicAdd(&counts[r * NDST + edst[g]], 1);
}

__global__ __launch_bounds__(1024) void scanA_k(const int* __restrict__ counts,
                                                int* __restrict__ offsets,
                                                int* __restrict__ btot) {
  __shared__ int wsum[16];
  int tid = threadIdx.x, lane = tid & 63, wid = tid >> 6;
  int i = blockIdx.x * 1024 + tid;
  int v = (i < NREL * NDST) ? counts[i] : 0;
  int x = v;
  #pragma unroll
  for (int off = 1; off < 64; off <<= 1) {
    int t = __shfl_up(x, off);
    if (lane >= off) x += t;
  }
  if (lane == 63) wsum[wid] = x;
  __syncthreads();
  if (wid == 0) {
    int t = (lane < 16) ? wsum[lane] : 0;
    #pragma unroll
    for (int off = 1; off < 16; off <<= 1) {
      int u = __shfl_up(t, off);
      if (lane >= off) t += u;
    }
    if (lane < 16) wsum[lane] = t;
  }
  __syncthreads();
  int wpre = (wid > 0) ? wsum[wid - 1] : 0;
  int incl = x + wpre;
  if (i < NREL * NDST) offsets[i] = incl - v;
  if (tid == 1023) btot[blockIdx.x] = incl;
}

__global__ void scanB_k(const int* __restrict__ btot, int* __restrict__ carry) {
  int lane = threadIdx.x;  // 64 threads = 1 wave
  int v = (lane < 40) ? btot[lane] : 0;
  int x = v;
  #pragma unroll
  for (int off = 1; off < 64; off <<= 1) {
    int t = __shfl_up(x, off);
    if (lane >= off) x += t;
  }
  if (lane < 40) carry[lane] = x - v;
}

__global__ __launch_bounds__(1024) void scanC_k(int* __restrict__ offsets,
                                                const int* __restrict__ carry,
                                                int* __restrict__ cursor) {
  int i = blockIdx.x * 1024 + threadIdx.x;
  if (i < NREL * NDST) {
    int o = offsets[i] + carry[blockIdx.x];
    offsets[i] = o;
    cursor[i] = o;
  }
  if (i == 0) offsets[NREL * NDST] = NREL * NEDGE;
}

__global__ void scatter_k(const int* __restrict__ esrc, const int* __restrict__ edst,
                          int* __restrict__ cursor, int* __restrict__ perm_src) {
  int g = blockIdx.x * 256 + threadIdx.x;
  if (g >= NREL * NEDGE) return;
  int r = g / NEDGE;
  int pos = atomicAdd(&cursor[r * NDST + edst[g]], 1);
  perm_src[pos] = esrc[g];
}

// ---------------- fused softmax + aggregate (+ output) ----------------
// MODE 0: batch (wave w = relation w), writes final out (mean + loop + bias + relu)
// MODE 1: serial (all waves on relation r_serial, edges strided), accumulates into agg
template <int MODE>
__global__ __launch_bounds__(256) void agg_k(const u16* __restrict__ hb, int ldcH,
                                             const int* __restrict__ offsets,
                                             const int* __restrict__ perm_src,
                                             const float* __restrict__ el,
                                             const float* __restrict__ er,
                                             const float* __restrict__ loop_o,
                                             const float* __restrict__ loop_b,
                                             float* __restrict__ outp,
                                             int r_serial, int first) {
  __shared__ float sacc[4][256];
  int d = blockIdx.x;
  int w = threadIdx.x >> 6, lane = threadIdx.x & 63;
  int r = (MODE == 0) ? w : r_serial;
  int rr = (MODE == 0) ? w : 0;
  int seg = r * NDST + d;
  int beg = offsets[seg], end = offsets[seg + 1];
  int head = lane >> 4;
  float a0 = 0.f, a1 = 0.f, a2 = 0.f, a3 = 0.f;
  if (beg < end) {
    float er0 = er[(size_t)d * 16 + r * 4 + 0];
    float er1 = er[(size_t)d * 16 + r * 4 + 1];
    float er2 = er[(size_t)d * 16 + r * 4 + 2];
    float er3 = er[(size_t)d * 16 + r * 4 + 3];
    float m0 = -1e30f, m1 = -1e30f, m2 = -1e30f, m3 = -1e30f;
    for (int i = beg + lane; i < end; i += 64) {
      int s = perm_src[i];
      float4 e4 = *(const float4*)(el + (size_t)s * 16 + r * 4);
      m0 = fmaxf(m0, leaky(e4.x + er0));
      m1 = fmaxf(m1, leaky(e4.y + er1));
      m2 = fmaxf(m2, leaky(e4.z + er2));
      m3 = fmaxf(m3, leaky(e4.w + er3));
    }
    #pragma unroll
    for (int off = 1; off < 64; off <<= 1) {
      m0 = fmaxf(m0, __shfl_xor(m0, off));
      m1 = fmaxf(m1, __shfl_xor(m1, off));
      m2 = fmaxf(m2, __shfl_xor(m2, off));
      m3 = fmaxf(m3, __shfl_xor(m3, off));
    }
    float s0 = 0.f, s1 = 0.f, s2 = 0.f, s3 = 0.f;
    for (int i = beg + lane; i < end; i += 64) {
      int s = perm_src[i];
      float4 e4 = *(const float4*)(el + (size_t)s * 16 + r * 4);
      s0 += __expf(leaky(e4.x + er0) - m0);
      s1 += __expf(leaky(e4.y + er1) - m1);
      s2 += __expf(leaky(e4.z + er2) - m2);
      s3 += __expf(leaky(e4.w + er3) - m3);
    }
    #pragma unroll
    for (int off = 1; off < 64; off <<= 1) {
      s0 += __shfl_xor(s0, off);
      s1 += __shfl_xor(s1, off);
      s2 += __shfl_xor(s2, off);
      s3 += __shfl_xor(s3, off);
    }
    float rd0 = 1.f / fmaxf(s0, 1e-9f), rd1 = 1.f / fmaxf(s1, 1e-9f);
    float rd2 = 1.f / fmaxf(s2, 1e-9f), rd3 = 1.f / fmaxf(s3, 1e-9f);
    float mh  = head == 0 ? m0 : head == 1 ? m1 : head == 2 ? m2 : m3;
    float rdh = head == 0 ? rd0 : head == 1 ? rd1 : head == 2 ? rd2 : rd3;
    float erh = head == 0 ? er0 : head == 1 ? er1 : head == 2 ? er2 : er3;
    int i0 = (MODE == 0) ? beg : beg + w;
    int stp = (MODE == 0) ? 1 : 4;
    for (int i = i0; i < end; i += stp) {
      int s = perm_src[i];
      float ev = el[(size_t)s * 16 + r * 4 + head];
      float a = __expf(leaky(ev + erh) - mh) * rdh;
      uint2 hv = *(const uint2*)(hb + (size_t)s * ldcH + rr * 256 + lane * 4);
      a0 = fmaf(a, b2f((u16)(hv.x & 0xffff)), a0);
      a1 = fmaf(a, b2f((u16)(hv.x >> 16)), a1);
      a2 = fmaf(a, b2f((u16)(hv.y & 0xffff)), a2);
      a3 = fmaf(a, b2f((u16)(hv.y >> 16)), a3);
    }
  }
  sacc[w][lane * 4 + 0] = a0;
  sacc[w][lane * 4 + 1] = a1;
  sacc[w][lane * 4 + 2] = a2;
  sacc[w][lane * 4 + 3] = a3;
  __syncthreads();
  int t = threadIdx.x;
  float v = sacc[0][t] + sacc[1][t] + sacc[2][t] + sacc[3][t];
  if (MODE == 0) {
    float o = v * 0.25f + loop_o[(size_t)d * 256 + t] + loop_b[t];
    outp[(size_t)d * 256 + t] = fmaxf(o, 0.f);
  } else {
    float* p = outp + (size_t)d * 256 + t;
    if (first) *p = v; else *p += v;
  }
}

__global__ __launch_bounds__(256) void final_k(const float* __restrict__ agg,
                                               const float* __restrict__ loop_o,
                                               const float* __restrict__ loop_b,
                                               float* __restrict__ out) {
  int i = blockIdx.x * 256 + threadIdx.x;
  float o = agg[i] * 0.25f + loop_o[i] + loop_b[i & 255];
  out[i] = fmaxf(o, 0.f);
}

// ---------------- launcher ----------------
extern "C" void kernel_launch(void* const* d_in, const int* in_sizes, int n_in,
                              void* d_out, int out_size, void* d_ws, size_t ws_size,
                              hipStream_t stream) {
  const float* x      = (const float*)d_in[0];
  const float* W      = (const float*)d_in[1];
  const float* attn_l = (const float*)d_in[2];
  const float* attn_r = (const float*)d_in[3];
  const float* loop_w = (const float*)d_in[4];
  const float* loop_b = (const float*)d_in[5];
  const int* edge_src = (const int*)d_in[6];
  const int* edge_dst = (const int*)d_in[7];
  float* out = (float*)d_out;

  char* wsp = (char*)d_ws;
  size_t off = 0;
  auto alloc = [&](size_t bytes) -> char* {
    char* p = wsp + off;
    off = (off + bytes + 255) & ~(size_t)255;
    return p;
  };
  u16* xb      = (u16*)alloc((size_t)NSRC * 256 * 2);
  u16* Wt      = (u16*)alloc((size_t)1280 * 256 * 2);
  float* el    = (float*)alloc((size_t)NSRC * 16 * 4);
  float* er    = (float*)alloc((size_t)NDST * 16 * 4);
  float* loopo = (float*)alloc((size_t)NDST * 256 * 4);
  int* counts  = (int*)alloc((size_t)NREL * NDST * 4);
  int* offs    = (int*)alloc((size_t)(NREL * NDST + 1) * 4);
  int* cursor  = (int*)alloc((size_t)NREL * NDST * 4);
  int* btot    = (int*)alloc(64 * 4);
  int* carry   = (int*)alloc(64 * 4);
  int* perm    = (int*)alloc((size_t)NREL * NEDGE * 4);

  bool batch = (off + (size_t)NSRC * 1024 * 2) <= ws_size;
  u16* hb; float* agg = nullptr;
  if (batch) {
    hb = (u16*)alloc((size_t)NSRC * 1024 * 2);
  } else {
    hb  = (u16*)alloc((size_t)NSRC * 256 * 2);
    agg = (float*)alloc((size_t)NDST * 256 * 4);
  }

  // conversions
  cvtx_k<<<NSRC * 256 / 4 / 256, 256, 0, stream>>>(x, xb);
  cvtw_k<<<1280, 256, 0, stream>>>(W, loop_w, Wt);

  // CSR (all relations)
  hipMemsetAsync(counts, 0, (size_t)NREL * NDST * 4, stream);
  const int EB = (NREL * NEDGE + 255) / 256;
  hist_k<<<EB, 256, 0, stream>>>(edge_dst, counts);
  scanA_k<<<40, 1024, 0, stream>>>(counts, offs, btot);
  scanB_k<<<1, 64, 0, stream>>>(btot, carry);
  scanC_k<<<40, 1024, 0, stream>>>(offs, carry, cursor);
  scatter_k<<<EB, 256, 0, stream>>>(edge_src, edge_dst, cursor, perm);

  // loop GEMM (f32 out)
  gemm_k<1><<<dim3(2, (NDST + 127) / 128), 256, 0, stream>>>(
      xb, Wt + (size_t)1024 * 256, loopo, NDST, 256);

  if (batch) {
    gemm_k<0><<<dim3(8, (NSRC + 127) / 128), 256, 0, stream>>>(xb, Wt, hb, NSRC, 1024);
    eler_k<<<(NSRC * NREL + 3) / 4, 256, 0, stream>>>(hb, 1024, 0, 4, attn_l, attn_r, el, er);
    agg_k<0><<<NDST, 256, 0, stream>>>(hb, 1024, offs, perm, el, er, loopo, loop_b, out, 0, 0);
  } else {
    for (int r = 0; r < NREL; ++r) {
      gemm_k<0><<<dim3(2, (NSRC + 127) / 128), 256, 0, stream>>>(
          xb, Wt + (size_t)r * 256 * 256, hb, NSRC, 256);
      eler_k<<<(NSRC + 3) / 4, 256, 0, stream>>>(hb, 256, r, 1, attn_l, attn_r, el, er);
      agg_k<1><<<NDST, 256, 0, stream>>>(hb, 256, offs, perm, el, er, nullptr, nullptr,
                                         agg, r, r == 0);
    }
    final_k<<<NDST, 256, 0, stream>>>(agg, loopo, loop_b, out);
  }
}

// Round 3
// 300.756 us; speedup vs baseline: 4.8016x; 1.1573x over previous
//
#include <hip/hip_runtime.h>

#define NSRC 50000
#define NDST 10000
#define NEDGE 250000
#define NREL 4
#define NEG_SLOPE 0.2f

typedef unsigned short u16;
typedef __attribute__((ext_vector_type(8))) short bf16x8;
typedef __attribute__((ext_vector_type(4))) float f32x4;

#define GLD16(g, l) __builtin_amdgcn_global_load_lds( \
    (__attribute__((address_space(1))) void*)(void*)(g), \
    (__attribute__((address_space(3))) void*)(l), 16, 0, 0)

static __device__ __forceinline__ u16 f2b(float f) {
  unsigned u = __float_as_uint(f);
  unsigned r = (u + 0x7FFFu + ((u >> 16) & 1u)) >> 16;
  return (u16)r;
}
static __device__ __forceinline__ float b2f(u16 b) {
  return __uint_as_float((unsigned)b << 16);
}
static __device__ __forceinline__ float leaky(float x) {
  return x > 0.f ? x : NEG_SLOPE * x;
}

// ---------------- conversions ----------------
__global__ __launch_bounds__(256) void cvtx_k(const float* __restrict__ x,
                                              u16* __restrict__ xb) {
  int i = blockIdx.x * 256 + threadIdx.x;  // group of 4 elements
  float4 v = ((const float4*)x)[i];
  uint2 o;
  o.x = (unsigned)f2b(v.x) | ((unsigned)f2b(v.y) << 16);
  o.y = (unsigned)f2b(v.z) | ((unsigned)f2b(v.w) << 16);
  ((uint2*)xb)[i] = o;
}

// Wt[row=mat*256+n][k] = bf16( mat<4 ? W[mat][k][n] : loop_w[k][n] )
__global__ __launch_bounds__(256) void cvtw_k(const float* __restrict__ W,
                                              const float* __restrict__ loop_w,
                                              u16* __restrict__ Wt) {
  int row = blockIdx.x;        // 0..1279
  int k = threadIdx.x;         // 0..255
  int mat = row >> 8, c = row & 255;
  float v = (mat < 4) ? W[(size_t)mat * 65536 + (size_t)k * 256 + c]
                      : loop_w[(size_t)k * 256 + c];
  Wt[(size_t)row * 256 + k] = f2b(v);
}

// WAt[c][k] (bf16, n-major, 128 rows; rows>=32 zero):
//   c<16 : el weights  W[r]@attn_l[r]  (r=c>>2, h=c&3)
//   16-31: er weights  W[r]@attn_r[r]
__global__ __launch_bounds__(256) void wa_k(const float* __restrict__ W,
                                            const float* __restrict__ al,
                                            const float* __restrict__ ar,
                                            u16* __restrict__ WAt) {
  int g = blockIdx.x * 256 + threadIdx.x;  // 0..32767
  int c = g >> 8, k = g & 255;
  float acc = 0.f;
  if (c < 32) {
    int cc = c & 15;
    int r = cc >> 2, h = cc & 3;
    const float* vec = ((c < 16) ? al : ar) + r * 256 + h * 64;
    const float* wrow = W + (size_t)r * 65536 + (size_t)k * 256 + h * 64;
    #pragma unroll 8
    for (int j = 0; j < 64; ++j) acc += wrow[j] * vec[j];
  }
  WAt[(size_t)c * 256 + k] = f2b(acc);
}

// ---------------- GEMM: C[M,*] = A[M,256](bf16) @ B^T, B n-major [n][k] ----------
// Tile 128x128, BK=64, 4 waves (2x2 of 64x64).
// OUTMODE 0: bf16 out (ldc)   1: f32 out (ldc)   2: f32 out, only cols<32 (ldc)
template <int OUTMODE>
__global__ __launch_bounds__(256) void gemm_k(const u16* __restrict__ A,
                                              const u16* __restrict__ B,
                                              void* __restrict__ C,
                                              int M, int ldc) {
  __shared__ u16 As[128 * 64];
  __shared__ u16 Bs[128 * 64];
  const int tid = threadIdx.x;
  const int w = tid >> 6, l = tid & 63;
  const int bm = blockIdx.y * 128, bn = blockIdx.x * 128;
  const int wm = (w >> 1) * 64, wn = (w & 1) * 64;
  f32x4 acc[4][4] = {};
  const int lrow = l >> 3, lchunk = l & 7;

  for (int t = 0; t < 4; ++t) {
    const int k0 = t * 64;
    #pragma unroll
    for (int c = 0; c < 4; ++c) {
      int rb = (w * 4 + c) * 8;
      int row_in = rb + lrow;
      int colb = (lchunk * 16) ^ ((row_in & 7) << 4);
      long arow = bm + row_in;
      if (arow >= M) arow = M - 1;
      const char* ga = (const char*)A + ((size_t)arow * 256 + k0) * 2 + colb;
      GLD16(ga, (char*)As + rb * 128);
      const char* gb = (const char*)B + ((size_t)(bn + row_in) * 256 + k0) * 2 + colb;
      GLD16(gb, (char*)Bs + rb * 128);
    }
    __syncthreads();
    #pragma unroll
    for (int kk = 0; kk < 2; ++kk) {
      bf16x8 af[4], bg[4];
      #pragma unroll
      for (int m = 0; m < 4; ++m) {
        int row = wm + m * 16 + (l & 15);
        int colb = (kk * 64 + ((l >> 4) * 16)) ^ ((row & 7) << 4);
        af[m] = *(const bf16x8*)((const char*)As + row * 128 + colb);
      }
      #pragma unroll
      for (int n = 0; n < 4; ++n) {
        int row = wn + n * 16 + (l & 15);
        int colb = (kk * 64 + ((l >> 4) * 16)) ^ ((row & 7) << 4);
        bg[n] = *(const bf16x8*)((const char*)Bs + row * 128 + colb);
      }
      #pragma unroll
      for (int m = 0; m < 4; ++m)
        #pragma unroll
        for (int n = 0; n < 4; ++n)
          acc[m][n] = __builtin_amdgcn_mfma_f32_16x16x32_bf16(af[m], bg[n], acc[m][n], 0, 0, 0);
    }
    __syncthreads();
  }
  #pragma unroll
  for (int m = 0; m < 4; ++m) {
    #pragma unroll
    for (int j = 0; j < 4; ++j) {
      int row = bm + wm + m * 16 + (l >> 4) * 4 + j;
      if (row < M) {
        #pragma unroll
        for (int n = 0; n < 4; ++n) {
          int col = bn + wn + n * 16 + (l & 15);
          if (OUTMODE == 0)
            ((u16*)C)[(size_t)row * ldc + col] = f2b(acc[m][n][j]);
          else if (OUTMODE == 1)
            ((float*)C)[(size_t)row * ldc + col] = acc[m][n][j];
          else {
            if (col < 32) ((float*)C)[(size_t)row * ldc + col] = acc[m][n][j];
          }
        }
      }
    }
  }
}

// ---------------- CSR build (all 4 relations at once) ----------------
__global__ void hist_k(const int* __restrict__ edst, int* __restrict__ counts) {
  int g = blockIdx.x * 256 + threadIdx.x;
  if (g >= NREL * NEDGE) return;
  int r = g / NEDGE;
  atomicAdd(&counts[r * NDST + edst[g]], 1);
}

__global__ __launch_bounds__(1024) void scanA_k(const int* __restrict__ counts,
                                                int* __restrict__ offsets,
                                                int* __restrict__ btot) {
  __shared__ int wsum[16];
  int tid = threadIdx.x, lane = tid & 63, wid = tid >> 6;
  int i = blockIdx.x * 1024 + tid;
  int v = (i < NREL * NDST) ? counts[i] : 0;
  int x = v;
  #pragma unroll
  for (int off = 1; off < 64; off <<= 1) {
    int t = __shfl_up(x, off);
    if (lane >= off) x += t;
  }
  if (lane == 63) wsum[wid] = x;
  __syncthreads();
  if (wid == 0) {
    int t = (lane < 16) ? wsum[lane] : 0;
    #pragma unroll
    for (int off = 1; off < 16; off <<= 1) {
      int u = __shfl_up(t, off);
      if (lane >= off) t += u;
    }
    if (lane < 16) wsum[lane] = t;
  }
  __syncthreads();
  int wpre = (wid > 0) ? wsum[wid - 1] : 0;
  int incl = x + wpre;
  if (i < NREL * NDST) offsets[i] = incl - v;
  if (tid == 1023) btot[blockIdx.x] = incl;
}

__global__ void scanB_k(const int* __restrict__ btot, int* __restrict__ carry) {
  int lane = threadIdx.x;  // 64 threads = 1 wave
  int v = (lane < 40) ? btot[lane] : 0;
  int x = v;
  #pragma unroll
  for (int off = 1; off < 64; off <<= 1) {
    int t = __shfl_up(x, off);
    if (lane >= off) x += t;
  }
  if (lane < 40) carry[lane] = x - v;
}

__global__ __launch_bounds__(1024) void scanC_k(int* __restrict__ offsets,
                                                const int* __restrict__ carry,
                                                int* __restrict__ cursor) {
  int i = blockIdx.x * 1024 + threadIdx.x;
  if (i < NREL * NDST) {
    int o = offsets[i] + carry[blockIdx.x];
    offsets[i] = o;
    cursor[i] = o;
  }
  if (i == 0) offsets[NREL * NDST] = NREL * NEDGE;
}

__global__ void scatter_k(const int* __restrict__ esrc, const int* __restrict__ edst,
                          int* __restrict__ cursor, int* __restrict__ perm_src) {
  int g = blockIdx.x * 256 + threadIdx.x;
  if (g >= NREL * NEDGE) return;
  int r = g / NEDGE;
  int pos = atomicAdd(&cursor[r * NDST + edst[g]], 1);
  perm_src[pos] = esrc[g];
}

// ---------------- fused softmax + aggregate + output ----------------
// Block = one dst (512 threads, 8 waves). Wave w: relation r=w&3, pair p=w>>2.
// Softmax without max-subtraction (|e| <~ 15, exp safe in f32, shift-invariant).
// Gather phase: half-wave (32 lanes, 16B/lane = 512B/edge) per edge, stride 4.
__global__ __launch_bounds__(512) void agg_k(const u16* __restrict__ hb,
                                             const int* __restrict__ offs,
                                             const int* __restrict__ perm,
                                             const float* __restrict__ elr,
                                             const u16* __restrict__ loopo,
                                             const float* __restrict__ loop_b,
                                             float* __restrict__ out) {
  __shared__ float sacc[8][256];
  __shared__ float ssum[8][4];
  const int d = blockIdx.x;
  const int tid = threadIdx.x;
  const int w = tid >> 6, lane = tid & 63;
  const int r = w & 3, p = w >> 2;
  const int seg = r * NDST + d;
  const int beg = offs[seg], end = offs[seg + 1];
  const float4 r4 = *(const float4*)(elr + (size_t)d * 32 + 16 + r * 4);

  // phase A: denom_h = sum over edges of exp(leaky(el_h + er_h))
  float s0 = 0.f, s1 = 0.f, s2 = 0.f, s3 = 0.f;
  for (int i = beg + p * 64 + lane; i < end; i += 128) {
    int s = perm[i];
    float4 l4 = *(const float4*)(elr + (size_t)s * 32 + r * 4);
    s0 += __expf(leaky(l4.x + r4.x));
    s1 += __expf(leaky(l4.y + r4.y));
    s2 += __expf(leaky(l4.z + r4.z));
    s3 += __expf(leaky(l4.w + r4.w));
  }
  #pragma unroll
  for (int off = 1; off < 64; off <<= 1) {
    s0 += __shfl_xor(s0, off);
    s1 += __shfl_xor(s1, off);
    s2 += __shfl_xor(s2, off);
    s3 += __shfl_xor(s3, off);
  }
  if (lane == 0) {
    ssum[w][0] = s0; ssum[w][1] = s1; ssum[w][2] = s2; ssum[w][3] = s3;
  }
  __syncthreads();

  // phase B: out_ch += alpha_e * h[src_e][ch], half-wave per edge
  const int lane32 = lane & 31;
  const int hw = p * 2 + (lane >> 5);
  const int head = lane32 >> 3;
  const float r4h = head == 0 ? r4.x : head == 1 ? r4.y : head == 2 ? r4.z : r4.w;
  const float dsum = ssum[r][head] + ssum[r + 4][head];
  const float rd = 1.f / fmaxf(dsum, 1e-9f);
  float a0 = 0.f, a1 = 0.f, a2 = 0.f, a3 = 0.f;
  float a4 = 0.f, a5 = 0.f, a6 = 0.f, a7 = 0.f;
  for (int i = beg + hw; i < end; i += 4) {
    int s = perm[i];
    float eh = elr[(size_t)s * 32 + r * 4 + head];
    float a = __expf(leaky(eh + r4h)) * rd;
    uint4 hv = *(const uint4*)(hb + (size_t)s * 1024 + r * 256 + lane32 * 8);
    a0 = fmaf(a, b2f((u16)(hv.x & 0xffff)), a0);
    a1 = fmaf(a, b2f((u16)(hv.x >> 16)), a1);
    a2 = fmaf(a, b2f((u16)(hv.y & 0xffff)), a2);
    a3 = fmaf(a, b2f((u16)(hv.y >> 16)), a3);
    a4 = fmaf(a, b2f((u16)(hv.z & 0xffff)), a4);
    a5 = fmaf(a, b2f((u16)(hv.z >> 16)), a5);
    a6 = fmaf(a, b2f((u16)(hv.w & 0xffff)), a6);
    a7 = fmaf(a, b2f((u16)(hv.w >> 16)), a7);
  }
  a0 += __shfl_xor(a0, 32); a1 += __shfl_xor(a1, 32);
  a2 += __shfl_xor(a2, 32); a3 += __shfl_xor(a3, 32);
  a4 += __shfl_xor(a4, 32); a5 += __shfl_xor(a5, 32);
  a6 += __shfl_xor(a6, 32); a7 += __shfl_xor(a7, 32);
  if (lane < 32) {
    float* pp = &sacc[w][lane32 * 8];
    pp[0] = a0; pp[1] = a1; pp[2] = a2; pp[3] = a3;
    pp[4] = a4; pp[5] = a5; pp[6] = a6; pp[7] = a7;
  }
  __syncthreads();
  if (tid < 256) {
    float v = 0.f;
    #pragma unroll
    for (int ww = 0; ww < 8; ++ww) v += sacc[ww][tid];
    float o = 0.25f * v + b2f(loopo[(size_t)d * 256 + tid]) + loop_b[tid];
    out[(size_t)d * 256 + tid] = fmaxf(o, 0.f);
  }
}

// ---------------- launcher ----------------
extern "C" void kernel_launch(void* const* d_in, const int* in_sizes, int n_in,
                              void* d_out, int out_size, void* d_ws, size_t ws_size,
                              hipStream_t stream) {
  const float* x      = (const float*)d_in[0];
  const float* W      = (const float*)d_in[1];
  const float* attn_l = (const float*)d_in[2];
  const float* attn_r = (const float*)d_in[3];
  const float* loop_w = (const float*)d_in[4];
  const float* loop_b = (const float*)d_in[5];
  const int* edge_src = (const int*)d_in[6];
  const int* edge_dst = (const int*)d_in[7];
  float* out = (float*)d_out;

  char* wsp = (char*)d_ws;
  size_t off = 0;
  auto alloc = [&](size_t bytes) -> char* {
    char* p = wsp + off;
    off = (off + bytes + 255) & ~(size_t)255;
    return p;
  };
  u16* xb      = (u16*)alloc((size_t)NSRC * 256 * 2);
  u16* Wt      = (u16*)alloc((size_t)1280 * 256 * 2);
  u16* WAt     = (u16*)alloc((size_t)128 * 256 * 2);
  float* elr   = (float*)alloc((size_t)NSRC * 32 * 4);
  u16* loopo   = (u16*)alloc((size_t)NDST * 256 * 2);
  int* counts  = (int*)alloc((size_t)NREL * NDST * 4);
  int* offs    = (int*)alloc((size_t)(NREL * NDST + 1) * 4);
  int* cursor  = (int*)alloc((size_t)NREL * NDST * 4);
  int* btot    = (int*)alloc(64 * 4);
  int* carry   = (int*)alloc(64 * 4);
  int* perm    = (int*)alloc((size_t)NREL * NEDGE * 4);
  u16* hb      = (u16*)alloc((size_t)NSRC * 1024 * 2);  // total ~144.7 MB

  // conversions / weight prep
  cvtx_k<<<NSRC * 256 / 4 / 256, 256, 0, stream>>>(x, xb);
  cvtw_k<<<1280, 256, 0, stream>>>(W, loop_w, Wt);
  wa_k<<<128, 256, 0, stream>>>(W, attn_l, attn_r, WAt);

  // CSR (all relations)
  hipMemsetAsync(counts, 0, (size_t)NREL * NDST * 4, stream);
  const int EB = (NREL * NEDGE + 255) / 256;
  hist_k<<<EB, 256, 0, stream>>>(edge_dst, counts);
  scanA_k<<<40, 1024, 0, stream>>>(counts, offs, btot);
  scanB_k<<<1, 64, 0, stream>>>(btot, carry);
  scanC_k<<<40, 1024, 0, stream>>>(offs, carry, cursor);
  scatter_k<<<EB, 256, 0, stream>>>(edge_src, edge_dst, cursor, perm);

  const int MB = (NSRC + 127) / 128;   // 391
  // el/er skinny GEMM: elr[NSRC][32] f32
  gemm_k<2><<<dim3(1, MB), 256, 0, stream>>>(xb, WAt, elr, NSRC, 32);
  // loop GEMM -> bf16 loopo
  gemm_k<0><<<dim3(2, (NDST + 127) / 128), 256, 0, stream>>>(
      xb, Wt + (size_t)1024 * 256, loopo, NDST, 256);
  // main batched GEMM: hb[NSRC][1024] bf16
  gemm_k<0><<<dim3(8, MB), 256, 0, stream>>>(xb, Wt, hb, NSRC, 1024);

  // fused softmax + aggregation + epilogue
  agg_k<<<NDST, 512, 0, stream>>>(hb, offs, perm, elr, loopo, loop_b, out);
}